// Round 2
// baseline (505.568 us; speedup 1.0000x reference)
//
#include <hip/hip_runtime.h>

#define HH 256
#define WW 256
#define CC 96
#define BB 8

__device__ __forceinline__ float silu_of(float z) {
    return z / (1.0f + __expf(-z));
}

__global__ __launch_bounds__(256, 5)
void trifreq_kernel(const float* __restrict__ x,
                    const float* __restrict__ w_lo,
                    const float* __restrict__ w_mf,
                    const float* __restrict__ w_hf,
                    const float* __restrict__ gamma,
                    const float* __restrict__ beta,
                    const float* __restrict__ mean,
                    const float* __restrict__ var,
                    float* __restrict__ out)
{
    // xs: input tile, tile-rel coords -4..67 -> idx = coord+4, stride 72.
    // Rows 72,73 + 16-float tail are uninitialized over-read pads: the mf band
    // stage vector-loads reach them, and the garbage flows only into tmp ring
    // rows/cols that the conv never reads.
    __shared__ __align__(16) float xs[74 * 72 + 16];      // 21.4 KB
    // tmp: one 32-output-row chunk of band values.
    // Chunk c0 holds band row coords R0..R0+35 where R0 = c0*32-1 (idx = coord-R0).
    // Conv for chunk c0 reads coords R0..R0+33 only; rows 34,35 are a write-only
    // ring. Col coords -1..66 -> idx = coord+1, stride 68 (col 65,66 = ring).
    __shared__ __align__(16) float tmp[36 * 68];          // 9.8 KB  (total 31.2 KB -> 5 blocks/CU)

    const int tid = threadIdx.x;
    const int tileIdx = blockIdx.x;          // 0..15
    const int c = blockIdx.y;                // 0..95 (concat order == input channel)
    const int b = blockIdx.z;                // 0..7
    const int th = (tileIdx >> 2) * 64;      // tile origin h
    const int tw = (tileIdx & 3) * 64;       // tile origin w

    const int g = c >> 5;                    // 0=lo,1=mf,2=hf
    const int ci = c & 31;
    const int c_out = ci * 3 + g;            // channel-shuffle output index

    const float* __restrict__ xin = x + (((size_t)b * CC + c) * (size_t)HH) * (size_t)WW;

    // BN constants (uniform per block -> scalar)
    const float bninv  = gamma[c_out] * rsqrtf(var[c_out] + 1e-5f);
    const float bnbias = beta[c_out] - mean[c_out] * bninv;

    // ---------------- stage input tile + halo(4), zero outside image ----------------
    for (int idx = tid; idx < 72 * 18; idx += 256) {
        const int r  = idx / 18;
        const int c4 = idx % 18;
        const int gh = th - 4 + r;
        const int gw = tw - 4 + 4 * c4;
        float4 v = make_float4(0.f, 0.f, 0.f, 0.f);
        if (gh >= 0 && gh < HH && gw >= 0 && gw + 3 < WW) {
            v = *reinterpret_cast<const float4*>(xin + (size_t)gh * WW + gw);
        }
        *reinterpret_cast<float4*>(&xs[r * 72 + 4 * c4]) = v;
    }
    __syncthreads();

    if (g == 0) {
        // ---------------- low band: direct 5x5 depthwise conv ----------------
        const int qr = (tid >> 4) << 2;   // 0..60
        const int qc = (tid & 15) << 2;   // 0..60
        const float* __restrict__ wp = w_lo + ci * 25;
        float wk[25];
        #pragma unroll
        for (int t = 0; t < 25; ++t) wk[t] = wp[t];
        float acc[4][4];
        #pragma unroll
        for (int i = 0; i < 4; ++i)
            #pragma unroll
            for (int j = 0; j < 4; ++j) acc[i][j] = 0.f;

        #pragma unroll
        for (int rr = 0; rr < 8; ++rr) {
            const float* row = &xs[(qr + rr + 2) * 72 + qc];
            float v[12];
            *reinterpret_cast<float4*>(&v[0]) = *reinterpret_cast<const float4*>(row);
            *reinterpret_cast<float4*>(&v[4]) = *reinterpret_cast<const float4*>(row + 4);
            *reinterpret_cast<float4*>(&v[8]) = *reinterpret_cast<const float4*>(row + 8);
            #pragma unroll
            for (int i = 0; i < 4; ++i) {
                const int ki = rr - i;
                if (ki >= 0 && ki < 5) {
                    #pragma unroll
                    for (int j = 0; j < 4; ++j)
                        acc[i][j] += v[j + 2] * wk[ki * 5 + 0]
                                   + v[j + 3] * wk[ki * 5 + 1]
                                   + v[j + 4] * wk[ki * 5 + 2]
                                   + v[j + 5] * wk[ki * 5 + 3]
                                   + v[j + 6] * wk[ki * 5 + 4];
                }
            }
        }

        float* __restrict__ op = out + (((size_t)b * CC + c_out) * (size_t)HH + (th + qr)) * (size_t)WW + (tw + qc);
        #pragma unroll
        for (int i = 0; i < 4; ++i) {
            float4 o;
            o.x = silu_of(acc[i][0] * bninv + bnbias);
            o.y = silu_of(acc[i][1] * bninv + bnbias);
            o.z = silu_of(acc[i][2] * bninv + bnbias);
            o.w = silu_of(acc[i][3] * bninv + bnbias);
            *reinterpret_cast<float4*>(op + (size_t)i * WW) = o;
        }
    } else {
        // 3x3 conv weights hoisted out of the chunk loop
        const float* __restrict__ wp = ((g == 1) ? w_mf : w_hf) + ci * 9;
        float wk[9];
        #pragma unroll
        for (int t = 0; t < 9; ++t) wk[t] = wp[t];

        for (int c0 = 0; c0 < 2; ++c0) {
            const int R0 = c0 * 32 - 1;      // band row coord of tmp idx 0

            // ------------- band stage: 9x17 patches (16-wide main + 9 tail) -------------
            if (tid < 153) {
                int pr, pc;
                if (tid < 144) { pr = tid >> 4; pc = tid & 15; }
                else           { pr = tid - 144; pc = 16; }
                const int bc = pc * 4 - 1;           // band col coord of j=0
                const int hb = th + R0 + pr * 4;     // band row coord (global) of i=0
                const int wb = tw + bc;              // band col coord (global) of j=0

                if (g == 1) {
                    // ---- mid band: bandpass = avg3 - avg7 ----
                    const int xrb = R0 + 1 + pr * 4;     // xs row idx of rr=0
                    float v7a[4][4] = {};
                    float v3a[4][4] = {};
                    #pragma unroll
                    for (int rr = 0; rr < 10; ++rr) {
                        const float* row = &xs[(xrb + rr) * 72 + pc * 4];
                        float v[12];
                        *reinterpret_cast<float4*>(&v[0]) = *reinterpret_cast<const float4*>(row);
                        *reinterpret_cast<float4*>(&v[4]) = *reinterpret_cast<const float4*>(row + 4);
                        *reinterpret_cast<float4*>(&v[8]) = *reinterpret_cast<const float4*>(row + 8);
                        float h7[4], h3[4];
                        float s = v[0] + v[1] + v[2] + v[3] + v[4] + v[5] + v[6];
                        h7[0] = s;
                        h7[1] = h7[0] + v[7] - v[0];
                        h7[2] = h7[1] + v[8] - v[1];
                        h7[3] = h7[2] + v[9] - v[2];
                        #pragma unroll
                        for (int j = 0; j < 4; ++j) h3[j] = v[j + 2] + v[j + 3] + v[j + 4];
                        #pragma unroll
                        for (int k = 0; k < 4; ++k) {
                            if (rr >= k && rr <= k + 6) {
                                #pragma unroll
                                for (int j = 0; j < 4; ++j) v7a[k][j] += h7[j];
                            }
                            if (rr >= k + 2 && rr <= k + 4) {
                                #pragma unroll
                                for (int j = 0; j < 4; ++j) v3a[k][j] += h3[j];
                            }
                        }
                    }
                    // reciprocal counts: interior fast path
                    float r3h[4], r7h[4], r3w[4], r7w[4];
                    if (hb >= 3 && hb + 6 <= HH - 1) {
                        #pragma unroll
                        for (int i = 0; i < 4; ++i) { r3h[i] = (1.f / 3.f); r7h[i] = (1.f / 7.f); }
                    } else {
                        #pragma unroll
                        for (int i = 0; i < 4; ++i) {
                            const int hh = hb + i;
                            const int a3 = min(hh + 1, HH - 1) - max(hh - 1, 0) + 1;
                            const int a7 = min(hh + 3, HH - 1) - max(hh - 3, 0) + 1;
                            r3h[i] = 1.0f / (float)a3;
                            r7h[i] = 1.0f / (float)a7;
                        }
                    }
                    if (wb >= 3 && wb + 6 <= WW - 1) {
                        #pragma unroll
                        for (int j = 0; j < 4; ++j) { r3w[j] = (1.f / 3.f); r7w[j] = (1.f / 7.f); }
                    } else {
                        #pragma unroll
                        for (int j = 0; j < 4; ++j) {
                            const int ww = wb + j;
                            const int a3 = min(ww + 1, WW - 1) - max(ww - 1, 0) + 1;
                            const int a7 = min(ww + 3, WW - 1) - max(ww - 3, 0) + 1;
                            r3w[j] = 1.0f / (float)a3;
                            r7w[j] = 1.0f / (float)a7;
                        }
                    }
                    #pragma unroll
                    for (int i = 0; i < 4; ++i) {
                        const int hh = hb + i;
                        float bpv[4];
                        #pragma unroll
                        for (int j = 0; j < 4; ++j) {
                            const int ww = wb + j;
                            float bp = 0.f;
                            if (hh >= 0 && hh < HH && ww >= 0 && ww < WW)
                                bp = v3a[i][j] * (r3h[i] * r3w[j]) - v7a[i][j] * (r7h[i] * r7w[j]);
                            bpv[j] = bp;
                        }
                        *reinterpret_cast<float4*>(&tmp[(pr * 4 + i) * 68 + pc * 4]) =
                            make_float4(bpv[0], bpv[1], bpv[2], bpv[3]);
                    }
                } else {
                    // ---- high band: highpass = x - avg3 ----
                    const int xrb = R0 + 3 + pr * 4;     // xs row idx of rr=0
                    float v3a[4][4] = {};
                    float cen[4][4];
                    #pragma unroll
                    for (int rr = 0; rr < 6; ++rr) {
                        const float* row = &xs[(xrb + rr) * 72 + pc * 4];
                        float v[8];
                        *reinterpret_cast<float4*>(&v[0]) = *reinterpret_cast<const float4*>(row);
                        *reinterpret_cast<float4*>(&v[4]) = *reinterpret_cast<const float4*>(row + 4);
                        float h3[4];
                        #pragma unroll
                        for (int j = 0; j < 4; ++j) h3[j] = v[j + 2] + v[j + 3] + v[j + 4];
                        if (rr >= 1 && rr <= 4) {
                            #pragma unroll
                            for (int j = 0; j < 4; ++j) cen[rr - 1][j] = v[j + 3];
                        }
                        #pragma unroll
                        for (int k = 0; k < 4; ++k) {
                            if (rr >= k && rr <= k + 2) {
                                #pragma unroll
                                for (int j = 0; j < 4; ++j) v3a[k][j] += h3[j];
                            }
                        }
                    }
                    float r3h[4], r3w[4];
                    if (hb >= 1 && hb + 4 <= HH - 1) {
                        #pragma unroll
                        for (int i = 0; i < 4; ++i) r3h[i] = (1.f / 3.f);
                    } else {
                        #pragma unroll
                        for (int i = 0; i < 4; ++i) {
                            const int hh = hb + i;
                            const int a3 = min(hh + 1, HH - 1) - max(hh - 1, 0) + 1;
                            r3h[i] = 1.0f / (float)a3;
                        }
                    }
                    if (wb >= 1 && wb + 4 <= WW - 1) {
                        #pragma unroll
                        for (int j = 0; j < 4; ++j) r3w[j] = (1.f / 3.f);
                    } else {
                        #pragma unroll
                        for (int j = 0; j < 4; ++j) {
                            const int ww = wb + j;
                            const int a3 = min(ww + 1, WW - 1) - max(ww - 1, 0) + 1;
                            r3w[j] = 1.0f / (float)a3;
                        }
                    }
                    #pragma unroll
                    for (int i = 0; i < 4; ++i) {
                        const int hh = hb + i;
                        float hpv[4];
                        #pragma unroll
                        for (int j = 0; j < 4; ++j) {
                            const int ww = wb + j;
                            float hp = 0.f;
                            if (hh >= 0 && hh < HH && ww >= 0 && ww < WW)
                                hp = cen[i][j] - v3a[i][j] * (r3h[i] * r3w[j]);
                            hpv[j] = hp;
                        }
                        *reinterpret_cast<float4*>(&tmp[(pr * 4 + i) * 68 + pc * 4]) =
                            make_float4(hpv[0], hpv[1], hpv[2], hpv[3]);
                    }
                }
            }
            __syncthreads();

            // ------------- 3x3 conv over this chunk: 2x4 patch per thread -------------
            const int lqr = (tid >> 4) * 2;   // local output row base 0..30
            const int qc  = (tid & 15) * 4;   // output col base 0..60
            float acc2[2][4];
            #pragma unroll
            for (int i = 0; i < 2; ++i)
                #pragma unroll
                for (int j = 0; j < 4; ++j) acc2[i][j] = 0.f;

            #pragma unroll
            for (int rr = 0; rr < 4; ++rr) {
                // band row coord = R0 + lqr + rr; cols coord qc-1.. -> idx qc..qc+5
                const float* row = &tmp[(lqr + rr) * 68 + qc];
                float v[8];
                *reinterpret_cast<float4*>(&v[0]) = *reinterpret_cast<const float4*>(row);
                *reinterpret_cast<float4*>(&v[4]) = *reinterpret_cast<const float4*>(row + 4);
                #pragma unroll
                for (int i = 0; i < 2; ++i) {
                    const int ki = rr - i;
                    if (ki >= 0 && ki < 3) {
                        #pragma unroll
                        for (int j = 0; j < 4; ++j)
                            acc2[i][j] += v[j + 0] * wk[ki * 3 + 0]
                                        + v[j + 1] * wk[ki * 3 + 1]
                                        + v[j + 2] * wk[ki * 3 + 2];
                    }
                }
            }

            // store this chunk's 2 rows
            float* __restrict__ op = out + (((size_t)b * CC + c_out) * (size_t)HH
                                            + (th + c0 * 32 + lqr)) * (size_t)WW + (tw + qc);
            #pragma unroll
            for (int i = 0; i < 2; ++i) {
                float4 o;
                o.x = silu_of(acc2[i][0] * bninv + bnbias);
                o.y = silu_of(acc2[i][1] * bninv + bnbias);
                o.z = silu_of(acc2[i][2] * bninv + bnbias);
                o.w = silu_of(acc2[i][3] * bninv + bnbias);
                *reinterpret_cast<float4*>(op + (size_t)i * WW) = o;
            }

            if (c0 == 0) __syncthreads();   // tmp reused by next chunk's band stage
        }
    }
}

extern "C" void kernel_launch(void* const* d_in, const int* in_sizes, int n_in,
                              void* d_out, int out_size, void* d_ws, size_t ws_size,
                              hipStream_t stream) {
    const float* x     = (const float*)d_in[0];
    const float* w_lo  = (const float*)d_in[1];
    const float* w_mf  = (const float*)d_in[2];
    const float* w_hf  = (const float*)d_in[3];
    const float* gam   = (const float*)d_in[4];
    const float* bet   = (const float*)d_in[5];
    const float* mea   = (const float*)d_in[6];
    const float* va    = (const float*)d_in[7];
    float* out = (float*)d_out;

    dim3 grid(16, CC, BB);
    dim3 block(256);
    hipLaunchKernelGGL(trifreq_kernel, grid, block, 0, stream,
                       x, w_lo, w_mf, w_hf, gam, bet, mea, va, out);
}

// Round 3
// 420.117 us; speedup vs baseline: 1.2034x; 1.2034x over previous
//
#include <hip/hip_runtime.h>

#define HH 256
#define WW 256
#define CC 96
#define BB 8

__device__ __forceinline__ float silu_of(float z) {
    return z / (1.0f + __expf(-z));
}

// NOTE launch_bounds: (256,4) — guarantee 4 blocks/CU for the allocator
// (VGPR budget 128 -> no spill; R2 with (256,5) spilled: VGPR 48 + 580 MB
// scratch traffic). Achieved occupancy is still 5 blocks/CU because LDS is
// 31.2 KB < 160/5 KB. Do NOT raise the 2nd arg.
__global__ __launch_bounds__(256, 4)
void trifreq_kernel(const float* __restrict__ x,
                    const float* __restrict__ w_lo,
                    const float* __restrict__ w_mf,
                    const float* __restrict__ w_hf,
                    const float* __restrict__ gamma,
                    const float* __restrict__ beta,
                    const float* __restrict__ mean,
                    const float* __restrict__ var,
                    float* __restrict__ out)
{
    // xs: input tile, tile-rel coords -4..67 -> idx = coord+4, stride 72.
    // Rows 72,73 + 16-float tail are uninitialized over-read pads: the mf band
    // stage vector-loads reach them, and the garbage flows only into tmp ring
    // rows/cols that the conv never reads.
    __shared__ __align__(16) float xs[74 * 72 + 16];      // 21.4 KB
    // tmp: one 32-output-row chunk of band values.
    // Chunk c0 holds band row coords R0..R0+35 where R0 = c0*32-1 (idx = coord-R0).
    // Conv for chunk c0 reads coords R0..R0+33 only; rows 34,35 are a write-only
    // ring. Col coords -1..66 -> idx = coord+1, stride 68 (col 65,66 = ring).
    __shared__ __align__(16) float tmp[36 * 68];          // 9.8 KB  (total 31.2 KB -> 5 blocks/CU)

    const int tid = threadIdx.x;
    const int tileIdx = blockIdx.x;          // 0..15
    const int c = blockIdx.y;                // 0..95 (concat order == input channel)
    const int b = blockIdx.z;                // 0..7
    const int th = (tileIdx >> 2) * 64;      // tile origin h
    const int tw = (tileIdx & 3) * 64;       // tile origin w

    const int g = c >> 5;                    // 0=lo,1=mf,2=hf
    const int ci = c & 31;
    const int c_out = ci * 3 + g;            // channel-shuffle output index

    const float* __restrict__ xin = x + (((size_t)b * CC + c) * (size_t)HH) * (size_t)WW;

    // ---------------- stage input tile + halo(4), zero outside image ----------------
    for (int idx = tid; idx < 72 * 18; idx += 256) {
        const int r  = idx / 18;
        const int c4 = idx % 18;
        const int gh = th - 4 + r;
        const int gw = tw - 4 + 4 * c4;
        float4 v = make_float4(0.f, 0.f, 0.f, 0.f);
        if (gh >= 0 && gh < HH && gw >= 0 && gw + 3 < WW) {
            v = *reinterpret_cast<const float4*>(xin + (size_t)gh * WW + gw);
        }
        *reinterpret_cast<float4*>(&xs[r * 72 + 4 * c4]) = v;
    }
    __syncthreads();

    if (g == 0) {
        // ---------------- low band: direct 5x5 depthwise conv ----------------
        const int qr = (tid >> 4) << 2;   // 0..60
        const int qc = (tid & 15) << 2;   // 0..60
        const float* __restrict__ wp = w_lo + ci * 25;
        float wk[25];
        #pragma unroll
        for (int t = 0; t < 25; ++t) wk[t] = wp[t];
        float acc[4][4];
        #pragma unroll
        for (int i = 0; i < 4; ++i)
            #pragma unroll
            for (int j = 0; j < 4; ++j) acc[i][j] = 0.f;

        #pragma unroll
        for (int rr = 0; rr < 8; ++rr) {
            const float* row = &xs[(qr + rr + 2) * 72 + qc];
            float v[12];
            *reinterpret_cast<float4*>(&v[0]) = *reinterpret_cast<const float4*>(row);
            *reinterpret_cast<float4*>(&v[4]) = *reinterpret_cast<const float4*>(row + 4);
            *reinterpret_cast<float4*>(&v[8]) = *reinterpret_cast<const float4*>(row + 8);
            #pragma unroll
            for (int i = 0; i < 4; ++i) {
                const int ki = rr - i;
                if (ki >= 0 && ki < 5) {
                    #pragma unroll
                    for (int j = 0; j < 4; ++j)
                        acc[i][j] += v[j + 2] * wk[ki * 5 + 0]
                                   + v[j + 3] * wk[ki * 5 + 1]
                                   + v[j + 4] * wk[ki * 5 + 2]
                                   + v[j + 5] * wk[ki * 5 + 3]
                                   + v[j + 6] * wk[ki * 5 + 4];
                }
            }
        }

        const float bninv  = gamma[c_out] * rsqrtf(var[c_out] + 1e-5f);
        const float bnbias = beta[c_out] - mean[c_out] * bninv;
        float* __restrict__ op = out + (((size_t)b * CC + c_out) * (size_t)HH + (th + qr)) * (size_t)WW + (tw + qc);
        #pragma unroll
        for (int i = 0; i < 4; ++i) {
            float4 o;
            o.x = silu_of(acc[i][0] * bninv + bnbias);
            o.y = silu_of(acc[i][1] * bninv + bnbias);
            o.z = silu_of(acc[i][2] * bninv + bnbias);
            o.w = silu_of(acc[i][3] * bninv + bnbias);
            *reinterpret_cast<float4*>(op + (size_t)i * WW) = o;
        }
    } else {
        for (int c0 = 0; c0 < 2; ++c0) {
            const int R0 = c0 * 32 - 1;      // band row coord of tmp idx 0

            // ------------- band stage: 9x17 patches (16-wide main + 9 tail) -------------
            if (tid < 153) {
                int pr, pc;
                if (tid < 144) { pr = tid >> 4; pc = tid & 15; }
                else           { pr = tid - 144; pc = 16; }
                const int bc = pc * 4 - 1;           // band col coord of j=0
                const int hb = th + R0 + pr * 4;     // band row coord (global) of i=0
                const int wb = tw + bc;              // band col coord (global) of j=0

                if (g == 1) {
                    // ---- mid band: bandpass = avg3 - avg7 ----
                    const int xrb = R0 + 1 + pr * 4;     // xs row idx of rr=0
                    float v7a[4][4] = {};
                    float v3a[4][4] = {};
                    #pragma unroll
                    for (int rr = 0; rr < 10; ++rr) {
                        const float* row = &xs[(xrb + rr) * 72 + pc * 4];
                        float v[12];
                        *reinterpret_cast<float4*>(&v[0]) = *reinterpret_cast<const float4*>(row);
                        *reinterpret_cast<float4*>(&v[4]) = *reinterpret_cast<const float4*>(row + 4);
                        *reinterpret_cast<float4*>(&v[8]) = *reinterpret_cast<const float4*>(row + 8);
                        float h7[4], h3[4];
                        float s = v[0] + v[1] + v[2] + v[3] + v[4] + v[5] + v[6];
                        h7[0] = s;
                        h7[1] = h7[0] + v[7] - v[0];
                        h7[2] = h7[1] + v[8] - v[1];
                        h7[3] = h7[2] + v[9] - v[2];
                        #pragma unroll
                        for (int j = 0; j < 4; ++j) h3[j] = v[j + 2] + v[j + 3] + v[j + 4];
                        #pragma unroll
                        for (int k = 0; k < 4; ++k) {
                            if (rr >= k && rr <= k + 6) {
                                #pragma unroll
                                for (int j = 0; j < 4; ++j) v7a[k][j] += h7[j];
                            }
                            if (rr >= k + 2 && rr <= k + 4) {
                                #pragma unroll
                                for (int j = 0; j < 4; ++j) v3a[k][j] += h3[j];
                            }
                        }
                    }
                    // reciprocal counts: interior fast path
                    float r3h[4], r7h[4], r3w[4], r7w[4];
                    if (hb >= 3 && hb + 6 <= HH - 1) {
                        #pragma unroll
                        for (int i = 0; i < 4; ++i) { r3h[i] = (1.f / 3.f); r7h[i] = (1.f / 7.f); }
                    } else {
                        #pragma unroll
                        for (int i = 0; i < 4; ++i) {
                            const int hh = hb + i;
                            const int a3 = min(hh + 1, HH - 1) - max(hh - 1, 0) + 1;
                            const int a7 = min(hh + 3, HH - 1) - max(hh - 3, 0) + 1;
                            r3h[i] = 1.0f / (float)a3;
                            r7h[i] = 1.0f / (float)a7;
                        }
                    }
                    if (wb >= 3 && wb + 6 <= WW - 1) {
                        #pragma unroll
                        for (int j = 0; j < 4; ++j) { r3w[j] = (1.f / 3.f); r7w[j] = (1.f / 7.f); }
                    } else {
                        #pragma unroll
                        for (int j = 0; j < 4; ++j) {
                            const int ww = wb + j;
                            const int a3 = min(ww + 1, WW - 1) - max(ww - 1, 0) + 1;
                            const int a7 = min(ww + 3, WW - 1) - max(ww - 3, 0) + 1;
                            r3w[j] = 1.0f / (float)a3;
                            r7w[j] = 1.0f / (float)a7;
                        }
                    }
                    #pragma unroll
                    for (int i = 0; i < 4; ++i) {
                        const int hh = hb + i;
                        float bpv[4];
                        #pragma unroll
                        for (int j = 0; j < 4; ++j) {
                            const int ww = wb + j;
                            float bp = 0.f;
                            if (hh >= 0 && hh < HH && ww >= 0 && ww < WW)
                                bp = v3a[i][j] * (r3h[i] * r3w[j]) - v7a[i][j] * (r7h[i] * r7w[j]);
                            bpv[j] = bp;
                        }
                        *reinterpret_cast<float4*>(&tmp[(pr * 4 + i) * 68 + pc * 4]) =
                            make_float4(bpv[0], bpv[1], bpv[2], bpv[3]);
                    }
                } else {
                    // ---- high band: highpass = x - avg3 ----
                    const int xrb = R0 + 3 + pr * 4;     // xs row idx of rr=0
                    float v3a[4][4] = {};
                    float cen[4][4];
                    #pragma unroll
                    for (int rr = 0; rr < 6; ++rr) {
                        const float* row = &xs[(xrb + rr) * 72 + pc * 4];
                        float v[8];
                        *reinterpret_cast<float4*>(&v[0]) = *reinterpret_cast<const float4*>(row);
                        *reinterpret_cast<float4*>(&v[4]) = *reinterpret_cast<const float4*>(row + 4);
                        float h3[4];
                        #pragma unroll
                        for (int j = 0; j < 4; ++j) h3[j] = v[j + 2] + v[j + 3] + v[j + 4];
                        if (rr >= 1 && rr <= 4) {
                            #pragma unroll
                            for (int j = 0; j < 4; ++j) cen[rr - 1][j] = v[j + 3];
                        }
                        #pragma unroll
                        for (int k = 0; k < 4; ++k) {
                            if (rr >= k && rr <= k + 2) {
                                #pragma unroll
                                for (int j = 0; j < 4; ++j) v3a[k][j] += h3[j];
                            }
                        }
                    }
                    float r3h[4], r3w[4];
                    if (hb >= 1 && hb + 4 <= HH - 1) {
                        #pragma unroll
                        for (int i = 0; i < 4; ++i) r3h[i] = (1.f / 3.f);
                    } else {
                        #pragma unroll
                        for (int i = 0; i < 4; ++i) {
                            const int hh = hb + i;
                            const int a3 = min(hh + 1, HH - 1) - max(hh - 1, 0) + 1;
                            r3h[i] = 1.0f / (float)a3;
                        }
                    }
                    if (wb >= 1 && wb + 4 <= WW - 1) {
                        #pragma unroll
                        for (int j = 0; j < 4; ++j) r3w[j] = (1.f / 3.f);
                    } else {
                        #pragma unroll
                        for (int j = 0; j < 4; ++j) {
                            const int ww = wb + j;
                            const int a3 = min(ww + 1, WW - 1) - max(ww - 1, 0) + 1;
                            r3w[j] = 1.0f / (float)a3;
                        }
                    }
                    #pragma unroll
                    for (int i = 0; i < 4; ++i) {
                        const int hh = hb + i;
                        float hpv[4];
                        #pragma unroll
                        for (int j = 0; j < 4; ++j) {
                            const int ww = wb + j;
                            float hp = 0.f;
                            if (hh >= 0 && hh < HH && ww >= 0 && ww < WW)
                                hp = cen[i][j] - v3a[i][j] * (r3h[i] * r3w[j]);
                            hpv[j] = hp;
                        }
                        *reinterpret_cast<float4*>(&tmp[(pr * 4 + i) * 68 + pc * 4]) =
                            make_float4(hpv[0], hpv[1], hpv[2], hpv[3]);
                    }
                }
            }
            __syncthreads();

            // ------------- 3x3 conv over this chunk: 2x4 patch per thread -------------
            // Weights/BN loaded HERE (after band stage) — keeps the band stage's
            // live set small; hoisting them contributed to R2's spill.
            const float* __restrict__ wp = ((g == 1) ? w_mf : w_hf) + ci * 9;
            float wk[9];
            #pragma unroll
            for (int t = 0; t < 9; ++t) wk[t] = wp[t];

            const int lqr = (tid >> 4) * 2;   // local output row base 0..30
            const int qc  = (tid & 15) * 4;   // output col base 0..60
            float acc2[2][4];
            #pragma unroll
            for (int i = 0; i < 2; ++i)
                #pragma unroll
                for (int j = 0; j < 4; ++j) acc2[i][j] = 0.f;

            #pragma unroll
            for (int rr = 0; rr < 4; ++rr) {
                // band row coord = R0 + lqr + rr; cols coord qc-1.. -> idx qc..qc+5
                const float* row = &tmp[(lqr + rr) * 68 + qc];
                float v[8];
                *reinterpret_cast<float4*>(&v[0]) = *reinterpret_cast<const float4*>(row);
                *reinterpret_cast<float4*>(&v[4]) = *reinterpret_cast<const float4*>(row + 4);
                #pragma unroll
                for (int i = 0; i < 2; ++i) {
                    const int ki = rr - i;
                    if (ki >= 0 && ki < 3) {
                        #pragma unroll
                        for (int j = 0; j < 4; ++j)
                            acc2[i][j] += v[j + 0] * wk[ki * 3 + 0]
                                        + v[j + 1] * wk[ki * 3 + 1]
                                        + v[j + 2] * wk[ki * 3 + 2];
                    }
                }
            }

            const float bninv  = gamma[c_out] * rsqrtf(var[c_out] + 1e-5f);
            const float bnbias = beta[c_out] - mean[c_out] * bninv;
            float* __restrict__ op = out + (((size_t)b * CC + c_out) * (size_t)HH
                                            + (th + c0 * 32 + lqr)) * (size_t)WW + (tw + qc);
            #pragma unroll
            for (int i = 0; i < 2; ++i) {
                float4 o;
                o.x = silu_of(acc2[i][0] * bninv + bnbias);
                o.y = silu_of(acc2[i][1] * bninv + bnbias);
                o.z = silu_of(acc2[i][2] * bninv + bnbias);
                o.w = silu_of(acc2[i][3] * bninv + bnbias);
                *reinterpret_cast<float4*>(op + (size_t)i * WW) = o;
            }

            if (c0 == 0) __syncthreads();   // tmp reused by next chunk's band stage
        }
    }
}

extern "C" void kernel_launch(void* const* d_in, const int* in_sizes, int n_in,
                              void* d_out, int out_size, void* d_ws, size_t ws_size,
                              hipStream_t stream) {
    const float* x     = (const float*)d_in[0];
    const float* w_lo  = (const float*)d_in[1];
    const float* w_mf  = (const float*)d_in[2];
    const float* w_hf  = (const float*)d_in[3];
    const float* gam   = (const float*)d_in[4];
    const float* bet   = (const float*)d_in[5];
    const float* mea   = (const float*)d_in[6];
    const float* va    = (const float*)d_in[7];
    float* out = (float*)d_out;

    dim3 grid(16, CC, BB);
    dim3 block(256);
    hipLaunchKernelGGL(trifreq_kernel, grid, block, 0, stream,
                       x, w_lo, w_mf, w_hf, gam, bet, mea, va, out);
}

// Round 4
// 416.338 us; speedup vs baseline: 1.2143x; 1.0091x over previous
//
#include <hip/hip_runtime.h>
#include <hip/hip_fp16.h>

#define HH 256
#define WW 256
#define CC 96
#define BB 8

__device__ __forceinline__ float silu_of(float z) {
    return z / (1.0f + __expf(-z));
}

// launch_bounds (256,4): allocator budget 128 VGPR -> lands at 64, no spill.
// (256,5) spilled catastrophically (R2: VGPR 48 + 580 MB scratch). Keep at 4;
// occupancy gain comes from LDS: 29.9 KB total -> 5 blocks/CU.
__global__ __launch_bounds__(256, 4)
void trifreq_kernel(const float* __restrict__ x,
                    const float* __restrict__ w_lo,
                    const float* __restrict__ w_mf,
                    const float* __restrict__ w_hf,
                    const float* __restrict__ gamma,
                    const float* __restrict__ beta,
                    const float* __restrict__ mean,
                    const float* __restrict__ var,
                    float* __restrict__ out)
{
    // xs: input tile, tile-rel coords -4..67 -> idx = coord+4, stride 72.
    // Rows 72,73 + 16-float tail are uninitialized over-read pads (mf band
    // vector loads); garbage flows only into tmp ring coords never read.
    __shared__ __align__(16) float xs[74 * 72 + 16];          // 21.4 KB
    // tmp: band/high-pass tile in FP16. coords -1..66 -> idx = coord+1,
    // stride 68. Conv reads coords -1..64 only (idx 0..65); idx 66,67 = ring.
    // fp16 band values: |bp| ~ O(1), rel err 4.9e-4 -> output err ~1e-3,
    // far under tolerance. Row byte stride 136 (8B-aligned -> b64 ok).
    __shared__ __align__(16) __half tmp[68 * 68 + 8];         // 9.3 KB (total 30.7 KB)

    const int tid = threadIdx.x;
    const int tileIdx = blockIdx.x;          // 0..15
    const int c = blockIdx.y;                // 0..95 (concat order == input channel)
    const int b = blockIdx.z;                // 0..7
    const int th = (tileIdx >> 2) * 64;      // tile origin h
    const int tw = (tileIdx & 3) * 64;       // tile origin w

    const int g = c >> 5;                    // 0=lo,1=mf,2=hf
    const int ci = c & 31;
    const int c_out = ci * 3 + g;            // channel-shuffle output index

    const float* __restrict__ xin = x + (((size_t)b * CC + c) * (size_t)HH) * (size_t)WW;

    // ---------------- stage input tile + halo(4), zero outside image ----------------
    for (int idx = tid; idx < 72 * 18; idx += 256) {
        const int r  = idx / 18;
        const int c4 = idx % 18;
        const int gh = th - 4 + r;
        const int gw = tw - 4 + 4 * c4;
        float4 v = make_float4(0.f, 0.f, 0.f, 0.f);
        if (gh >= 0 && gh < HH && gw >= 0 && gw + 3 < WW) {
            v = *reinterpret_cast<const float4*>(xin + (size_t)gh * WW + gw);
        }
        *reinterpret_cast<float4*>(&xs[r * 72 + 4 * c4]) = v;
    }
    __syncthreads();

    const int qr = (tid >> 4) << 2;   // output patch base row (0..60)
    const int qc = (tid & 15) << 2;   // output patch base col (0..60)
    float acc[4][4];

    if (g == 0) {
        // ---------------- low band: direct 5x5 depthwise conv ----------------
        const float* __restrict__ wp = w_lo + ci * 25;
        float wk[25];
        #pragma unroll
        for (int t = 0; t < 25; ++t) wk[t] = wp[t];
        #pragma unroll
        for (int i = 0; i < 4; ++i)
            #pragma unroll
            for (int j = 0; j < 4; ++j) acc[i][j] = 0.f;

        #pragma unroll
        for (int rr = 0; rr < 8; ++rr) {
            const float* row = &xs[(qr + rr + 2) * 72 + qc];
            float v[12];
            *reinterpret_cast<float4*>(&v[0]) = *reinterpret_cast<const float4*>(row);
            *reinterpret_cast<float4*>(&v[4]) = *reinterpret_cast<const float4*>(row + 4);
            *reinterpret_cast<float4*>(&v[8]) = *reinterpret_cast<const float4*>(row + 8);
            #pragma unroll
            for (int i = 0; i < 4; ++i) {
                const int ki = rr - i;
                if (ki >= 0 && ki < 5) {
                    #pragma unroll
                    for (int j = 0; j < 4; ++j)
                        acc[i][j] += v[j + 2] * wk[ki * 5 + 0]
                                   + v[j + 3] * wk[ki * 5 + 1]
                                   + v[j + 4] * wk[ki * 5 + 2]
                                   + v[j + 5] * wk[ki * 5 + 3]
                                   + v[j + 6] * wk[ki * 5 + 4];
                }
            }
        }
    } else {
        if (g == 1) {
            // ---------------- mid band: bandpass = avg3 - avg7 into tmp ----------------
            for (int p = tid; p < 17 * 17; p += 256) {
                const int pr = p / 17, pc = p % 17;
                const int br = pr * 4 - 1, bc = pc * 4 - 1;   // tmp coord base (ring off = 1)
                const int hb = th + br;                       // global band row of i=0
                const int wb = tw + bc;                       // global band col of j=0
                float v7a[4][4] = {};
                float v3a[4][4] = {};
                #pragma unroll
                for (int rr = 0; rr < 10; ++rr) {
                    const float* row = &xs[(pr * 4 + rr) * 72 + pc * 4];
                    float v[12];
                    *reinterpret_cast<float4*>(&v[0]) = *reinterpret_cast<const float4*>(row);
                    *reinterpret_cast<float4*>(&v[4]) = *reinterpret_cast<const float4*>(row + 4);
                    *reinterpret_cast<float4*>(&v[8]) = *reinterpret_cast<const float4*>(row + 8);
                    float h7[4], h3[4];
                    float s = v[0] + v[1] + v[2] + v[3] + v[4] + v[5] + v[6];
                    h7[0] = s;
                    h7[1] = h7[0] + v[7] - v[0];
                    h7[2] = h7[1] + v[8] - v[1];
                    h7[3] = h7[2] + v[9] - v[2];
                    #pragma unroll
                    for (int j = 0; j < 4; ++j) h3[j] = v[j + 2] + v[j + 3] + v[j + 4];
                    #pragma unroll
                    for (int k = 0; k < 4; ++k) {
                        if (rr >= k && rr <= k + 6) {
                            #pragma unroll
                            for (int j = 0; j < 4; ++j) v7a[k][j] += h7[j];
                        }
                        if (rr >= k + 2 && rr <= k + 4) {
                            #pragma unroll
                            for (int j = 0; j < 4; ++j) v3a[k][j] += h3[j];
                        }
                    }
                }
                // count_include_pad=False reciprocals: interior fast path
                float r3h[4], r7h[4], r3w[4], r7w[4];
                if (hb >= 3 && hb + 6 <= HH - 1) {
                    #pragma unroll
                    for (int i = 0; i < 4; ++i) { r3h[i] = (1.f / 3.f); r7h[i] = (1.f / 7.f); }
                } else {
                    #pragma unroll
                    for (int i = 0; i < 4; ++i) {
                        const int hh = hb + i;
                        const int a3 = min(hh + 1, HH - 1) - max(hh - 1, 0) + 1;
                        const int a7 = min(hh + 3, HH - 1) - max(hh - 3, 0) + 1;
                        r3h[i] = 1.0f / (float)a3;
                        r7h[i] = 1.0f / (float)a7;
                    }
                }
                if (wb >= 3 && wb + 6 <= WW - 1) {
                    #pragma unroll
                    for (int j = 0; j < 4; ++j) { r3w[j] = (1.f / 3.f); r7w[j] = (1.f / 7.f); }
                } else {
                    #pragma unroll
                    for (int j = 0; j < 4; ++j) {
                        const int ww = wb + j;
                        const int a3 = min(ww + 1, WW - 1) - max(ww - 1, 0) + 1;
                        const int a7 = min(ww + 3, WW - 1) - max(ww - 3, 0) + 1;
                        r3w[j] = 1.0f / (float)a3;
                        r7w[j] = 1.0f / (float)a7;
                    }
                }
                #pragma unroll
                for (int i = 0; i < 4; ++i) {
                    const int hh = hb + i;
                    float bpv[4];
                    #pragma unroll
                    for (int j = 0; j < 4; ++j) {
                        const int ww = wb + j;
                        float bp = 0.f;
                        if (hh >= 0 && hh < HH && ww >= 0 && ww < WW)
                            bp = v3a[i][j] * (r3h[i] * r3w[j]) - v7a[i][j] * (r7h[i] * r7w[j]);
                        bpv[j] = bp;
                    }
                    __half2* trow = reinterpret_cast<__half2*>(&tmp[(pr * 4 + i) * 68 + pc * 4]);
                    trow[0] = __floats2half2_rn(bpv[0], bpv[1]);
                    trow[1] = __floats2half2_rn(bpv[2], bpv[3]);
                }
            }
        } else {
            // ---------------- high band: highpass = x - avg3 into tmp ----------------
            for (int p = tid; p < 17 * 17; p += 256) {
                const int pr = p / 17, pc = p % 17;
                const int br = pr * 4 - 1, bc = pc * 4 - 1;
                const int hb = th + br;
                const int wb = tw + bc;
                float v3a[4][4] = {};
                float cen[4][4];
                #pragma unroll
                for (int rr = 0; rr < 6; ++rr) {
                    const float* row = &xs[(pr * 4 + 2 + rr) * 72 + pc * 4];
                    float v[8];
                    *reinterpret_cast<float4*>(&v[0]) = *reinterpret_cast<const float4*>(row);
                    *reinterpret_cast<float4*>(&v[4]) = *reinterpret_cast<const float4*>(row + 4);
                    float h3[4];
                    #pragma unroll
                    for (int j = 0; j < 4; ++j) h3[j] = v[j + 2] + v[j + 3] + v[j + 4];
                    if (rr >= 1 && rr <= 4) {
                        #pragma unroll
                        for (int j = 0; j < 4; ++j) cen[rr - 1][j] = v[j + 3];
                    }
                    #pragma unroll
                    for (int k = 0; k < 4; ++k) {
                        if (rr >= k && rr <= k + 2) {
                            #pragma unroll
                            for (int j = 0; j < 4; ++j) v3a[k][j] += h3[j];
                        }
                    }
                }
                float r3h[4], r3w[4];
                if (hb >= 1 && hb + 4 <= HH - 1) {
                    #pragma unroll
                    for (int i = 0; i < 4; ++i) r3h[i] = (1.f / 3.f);
                } else {
                    #pragma unroll
                    for (int i = 0; i < 4; ++i) {
                        const int hh = hb + i;
                        const int a3 = min(hh + 1, HH - 1) - max(hh - 1, 0) + 1;
                        r3h[i] = 1.0f / (float)a3;
                    }
                }
                if (wb >= 1 && wb + 4 <= WW - 1) {
                    #pragma unroll
                    for (int j = 0; j < 4; ++j) r3w[j] = (1.f / 3.f);
                } else {
                    #pragma unroll
                    for (int j = 0; j < 4; ++j) {
                        const int ww = wb + j;
                        const int a3 = min(ww + 1, WW - 1) - max(ww - 1, 0) + 1;
                        r3w[j] = 1.0f / (float)a3;
                    }
                }
                #pragma unroll
                for (int i = 0; i < 4; ++i) {
                    const int hh = hb + i;
                    float hpv[4];
                    #pragma unroll
                    for (int j = 0; j < 4; ++j) {
                        const int ww = wb + j;
                        float hp = 0.f;
                        if (hh >= 0 && hh < HH && ww >= 0 && ww < WW)
                            hp = cen[i][j] - v3a[i][j] * (r3h[i] * r3w[j]);
                        hpv[j] = hp;
                    }
                    __half2* trow = reinterpret_cast<__half2*>(&tmp[(pr * 4 + i) * 68 + pc * 4]);
                    trow[0] = __floats2half2_rn(hpv[0], hpv[1]);
                    trow[1] = __floats2half2_rn(hpv[2], hpv[3]);
                }
            }
        }
        __syncthreads();

        // ---------------- 3x3 depthwise conv over tmp (fp16 -> f32) ----------------
        const float* __restrict__ wp = ((g == 1) ? w_mf : w_hf) + ci * 9;
        float wk[9];
        #pragma unroll
        for (int t = 0; t < 9; ++t) wk[t] = wp[t];
        #pragma unroll
        for (int i = 0; i < 4; ++i)
            #pragma unroll
            for (int j = 0; j < 4; ++j) acc[i][j] = 0.f;

        #pragma unroll
        for (int rr = 0; rr < 6; ++rr) {
            // tmp row coord = qr-1+rr -> idx qr+rr; cols coord qc-1.. -> idx qc..qc+5
            const __half2* hrow = reinterpret_cast<const __half2*>(&tmp[(qr + rr) * 68 + qc]);
            const float2 va = __half22float2(hrow[0]);
            const float2 vb = __half22float2(hrow[1]);
            const float2 vc = __half22float2(hrow[2]);
            float v[6];
            v[0] = va.x; v[1] = va.y; v[2] = vb.x; v[3] = vb.y; v[4] = vc.x; v[5] = vc.y;
            #pragma unroll
            for (int i = 0; i < 4; ++i) {
                const int ki = rr - i;
                if (ki >= 0 && ki < 3) {
                    #pragma unroll
                    for (int j = 0; j < 4; ++j)
                        acc[i][j] += v[j + 0] * wk[ki * 3 + 0]
                                   + v[j + 1] * wk[ki * 3 + 1]
                                   + v[j + 2] * wk[ki * 3 + 2];
                }
            }
        }
    }

    // ---------------- BN + SiLU + store (channel-shuffled) ----------------
    const float bninv  = gamma[c_out] * rsqrtf(var[c_out] + 1e-5f);
    const float bnbias = beta[c_out] - mean[c_out] * bninv;
    float* __restrict__ op = out + (((size_t)b * CC + c_out) * (size_t)HH + (th + qr)) * (size_t)WW + (tw + qc);
    #pragma unroll
    for (int i = 0; i < 4; ++i) {
        float4 o;
        o.x = silu_of(acc[i][0] * bninv + bnbias);
        o.y = silu_of(acc[i][1] * bninv + bnbias);
        o.z = silu_of(acc[i][2] * bninv + bnbias);
        o.w = silu_of(acc[i][3] * bninv + bnbias);
        *reinterpret_cast<float4*>(op + (size_t)i * WW) = o;
    }
}

extern "C" void kernel_launch(void* const* d_in, const int* in_sizes, int n_in,
                              void* d_out, int out_size, void* d_ws, size_t ws_size,
                              hipStream_t stream) {
    const float* x     = (const float*)d_in[0];
    const float* w_lo  = (const float*)d_in[1];
    const float* w_mf  = (const float*)d_in[2];
    const float* w_hf  = (const float*)d_in[3];
    const float* gam   = (const float*)d_in[4];
    const float* bet   = (const float*)d_in[5];
    const float* mea   = (const float*)d_in[6];
    const float* va    = (const float*)d_in[7];
    float* out = (float*)d_out;

    dim3 grid(16, CC, BB);
    dim3 block(256);
    hipLaunchKernelGGL(trifreq_kernel, grid, block, 0, stream,
                       x, w_lo, w_mf, w_hf, gam, bet, mea, va, out);
}

// Round 5
// 400.411 us; speedup vs baseline: 1.2626x; 1.0398x over previous
//
#include <hip/hip_runtime.h>
#include <hip/hip_fp16.h>

#define HH 256
#define WW 256
#define CC 96
#define BB 8

__device__ __forceinline__ float silu_of(float z) {
    return z / (1.0f + __expf(-z));
}

// launch_bounds (256,4): allocator budget 128 VGPR -> lands at 64, no spill.
// (256,5) spilled catastrophically (R2). Keep at 4.
// DO NOT add branchy "interior fast path" reciprocal init: divergent-CF merges
// of the r3h/r7h arrays demote them to scratch (R2/R3/R4: +100..160 MB
// FETCH/WRITE, -13% VALUBusy). Unconditional min/max formulas stay in regs.
__global__ __launch_bounds__(256, 4)
void trifreq_kernel(const float* __restrict__ x,
                    const float* __restrict__ w_lo,
                    const float* __restrict__ w_mf,
                    const float* __restrict__ w_hf,
                    const float* __restrict__ gamma,
                    const float* __restrict__ beta,
                    const float* __restrict__ mean,
                    const float* __restrict__ var,
                    float* __restrict__ out)
{
    // xs: input tile, tile-rel coords -4..67 -> idx = coord+4, stride 72.
    // Rows 72,73 + 16-float tail are uninitialized over-read pads (mf band
    // vector loads); garbage flows only into tmp ring coords never read.
    __shared__ __align__(16) float xs[74 * 72 + 16];          // 21.4 KB
    // tmp: band/high-pass tile in FP16. coords -1..66 -> idx = coord+1,
    // stride 68. Conv reads coords -1..64 (idx 0..65); idx 66,67 = ring.
    // fp16 band values: |bp| O(1), rel err ~5e-4 -> output err ~1e-3 (absmax
    // 0.031 passed in R4). Row byte stride 136 = 17*8 -> 8B-aligned rows.
    __shared__ __align__(16) __half tmp[68 * 68 + 8];         // 9.3 KB (total 30.7 KB -> 5 blocks/CU)

    const int tid = threadIdx.x;
    const int tileIdx = blockIdx.x;          // 0..15
    const int c = blockIdx.y;                // 0..95 (concat order == input channel)
    const int b = blockIdx.z;                // 0..7
    const int th = (tileIdx >> 2) * 64;      // tile origin h
    const int tw = (tileIdx & 3) * 64;       // tile origin w

    const int g = c >> 5;                    // 0=lo,1=mf,2=hf
    const int ci = c & 31;
    const int c_out = ci * 3 + g;            // channel-shuffle output index

    const float* __restrict__ xin = x + (((size_t)b * CC + c) * (size_t)HH) * (size_t)WW;

    // ---------------- stage input tile + halo(4), zero outside image ----------------
    for (int idx = tid; idx < 72 * 18; idx += 256) {
        const int r  = idx / 18;
        const int c4 = idx % 18;
        const int gh = th - 4 + r;
        const int gw = tw - 4 + 4 * c4;
        float4 v = make_float4(0.f, 0.f, 0.f, 0.f);
        if (gh >= 0 && gh < HH && gw >= 0 && gw + 3 < WW) {
            v = *reinterpret_cast<const float4*>(xin + (size_t)gh * WW + gw);
        }
        *reinterpret_cast<float4*>(&xs[r * 72 + 4 * c4]) = v;
    }
    __syncthreads();

    const int qr = (tid >> 4) << 2;   // output patch base row (0..60)
    const int qc = (tid & 15) << 2;   // output patch base col (0..60)
    float acc[4][4];

    if (g == 0) {
        // ---------------- low band: direct 5x5 depthwise conv ----------------
        const float* __restrict__ wp = w_lo + ci * 25;
        float wk[25];
        #pragma unroll
        for (int t = 0; t < 25; ++t) wk[t] = wp[t];
        #pragma unroll
        for (int i = 0; i < 4; ++i)
            #pragma unroll
            for (int j = 0; j < 4; ++j) acc[i][j] = 0.f;

        #pragma unroll
        for (int rr = 0; rr < 8; ++rr) {
            const float* row = &xs[(qr + rr + 2) * 72 + qc];
            float v[12];
            *reinterpret_cast<float4*>(&v[0]) = *reinterpret_cast<const float4*>(row);
            *reinterpret_cast<float4*>(&v[4]) = *reinterpret_cast<const float4*>(row + 4);
            *reinterpret_cast<float4*>(&v[8]) = *reinterpret_cast<const float4*>(row + 8);
            #pragma unroll
            for (int i = 0; i < 4; ++i) {
                const int ki = rr - i;
                if (ki >= 0 && ki < 5) {
                    #pragma unroll
                    for (int j = 0; j < 4; ++j)
                        acc[i][j] += v[j + 2] * wk[ki * 5 + 0]
                                   + v[j + 3] * wk[ki * 5 + 1]
                                   + v[j + 4] * wk[ki * 5 + 2]
                                   + v[j + 5] * wk[ki * 5 + 3]
                                   + v[j + 6] * wk[ki * 5 + 4];
                }
            }
        }
    } else {
        if (g == 1) {
            // ---------------- mid band: bandpass = avg3 - avg7 into tmp ----------------
            for (int p = tid; p < 17 * 17; p += 256) {
                const int pr = p / 17, pc = p % 17;
                const int br = pr * 4 - 1, bc = pc * 4 - 1;   // tmp coord base (ring off = 1)
                float v7a[4][4] = {};
                float v3a[4][4] = {};
                #pragma unroll
                for (int rr = 0; rr < 10; ++rr) {
                    const float* row = &xs[(pr * 4 + rr) * 72 + pc * 4];
                    float v[12];
                    *reinterpret_cast<float4*>(&v[0]) = *reinterpret_cast<const float4*>(row);
                    *reinterpret_cast<float4*>(&v[4]) = *reinterpret_cast<const float4*>(row + 4);
                    *reinterpret_cast<float4*>(&v[8]) = *reinterpret_cast<const float4*>(row + 8);
                    float h7[4], h3[4];
                    float s = v[0] + v[1] + v[2] + v[3] + v[4] + v[5] + v[6];
                    h7[0] = s;
                    h7[1] = h7[0] + v[7] - v[0];
                    h7[2] = h7[1] + v[8] - v[1];
                    h7[3] = h7[2] + v[9] - v[2];
                    #pragma unroll
                    for (int j = 0; j < 4; ++j) h3[j] = v[j + 2] + v[j + 3] + v[j + 4];
                    #pragma unroll
                    for (int k = 0; k < 4; ++k) {
                        if (rr >= k && rr <= k + 6) {
                            #pragma unroll
                            for (int j = 0; j < 4; ++j) v7a[k][j] += h7[j];
                        }
                        if (rr >= k + 2 && rr <= k + 4) {
                            #pragma unroll
                            for (int j = 0; j < 4; ++j) v3a[k][j] += h3[j];
                        }
                    }
                }
                // count_include_pad=False reciprocal counts (unconditional — see note)
                float r3h[4], r7h[4], r3w[4], r7w[4];
                #pragma unroll
                for (int i = 0; i < 4; ++i) {
                    const int hh = th + br + i;
                    const int a3 = min(hh + 1, HH - 1) - max(hh - 1, 0) + 1;
                    const int a7 = min(hh + 3, HH - 1) - max(hh - 3, 0) + 1;
                    r3h[i] = 1.0f / (float)a3;
                    r7h[i] = 1.0f / (float)a7;
                }
                #pragma unroll
                for (int j = 0; j < 4; ++j) {
                    const int ww = tw + bc + j;
                    const int a3 = min(ww + 1, WW - 1) - max(ww - 1, 0) + 1;
                    const int a7 = min(ww + 3, WW - 1) - max(ww - 3, 0) + 1;
                    r3w[j] = 1.0f / (float)a3;
                    r7w[j] = 1.0f / (float)a7;
                }
                #pragma unroll
                for (int i = 0; i < 4; ++i) {
                    const int hh = th + br + i;
                    float bpv[4];
                    #pragma unroll
                    for (int j = 0; j < 4; ++j) {
                        const int ww = tw + bc + j;
                        float bp = 0.f;
                        if (hh >= 0 && hh < HH && ww >= 0 && ww < WW)
                            bp = v3a[i][j] * (r3h[i] * r3w[j]) - v7a[i][j] * (r7h[i] * r7w[j]);
                        bpv[j] = bp;
                    }
                    __half2* trow = reinterpret_cast<__half2*>(&tmp[(pr * 4 + i) * 68 + pc * 4]);
                    trow[0] = __floats2half2_rn(bpv[0], bpv[1]);
                    trow[1] = __floats2half2_rn(bpv[2], bpv[3]);
                }
            }
        } else {
            // ---------------- high band: highpass = x - avg3 into tmp ----------------
            for (int p = tid; p < 17 * 17; p += 256) {
                const int pr = p / 17, pc = p % 17;
                const int br = pr * 4 - 1, bc = pc * 4 - 1;
                float v3a[4][4] = {};
                float cen[4][4];
                #pragma unroll
                for (int rr = 0; rr < 6; ++rr) {
                    const float* row = &xs[(pr * 4 + 2 + rr) * 72 + pc * 4];
                    float v[8];
                    *reinterpret_cast<float4*>(&v[0]) = *reinterpret_cast<const float4*>(row);
                    *reinterpret_cast<float4*>(&v[4]) = *reinterpret_cast<const float4*>(row + 4);
                    float h3[4];
                    #pragma unroll
                    for (int j = 0; j < 4; ++j) h3[j] = v[j + 2] + v[j + 3] + v[j + 4];
                    if (rr >= 1 && rr <= 4) {
                        #pragma unroll
                        for (int j = 0; j < 4; ++j) cen[rr - 1][j] = v[j + 3];
                    }
                    #pragma unroll
                    for (int k = 0; k < 4; ++k) {
                        if (rr >= k && rr <= k + 2) {
                            #pragma unroll
                            for (int j = 0; j < 4; ++j) v3a[k][j] += h3[j];
                        }
                    }
                }
                float r3h[4], r3w[4];
                #pragma unroll
                for (int i = 0; i < 4; ++i) {
                    const int hh = th + br + i;
                    const int a3 = min(hh + 1, HH - 1) - max(hh - 1, 0) + 1;
                    r3h[i] = 1.0f / (float)a3;
                }
                #pragma unroll
                for (int j = 0; j < 4; ++j) {
                    const int ww = tw + bc + j;
                    const int a3 = min(ww + 1, WW - 1) - max(ww - 1, 0) + 1;
                    r3w[j] = 1.0f / (float)a3;
                }
                #pragma unroll
                for (int i = 0; i < 4; ++i) {
                    const int hh = th + br + i;
                    float hpv[4];
                    #pragma unroll
                    for (int j = 0; j < 4; ++j) {
                        const int ww = tw + bc + j;
                        float hp = 0.f;
                        if (hh >= 0 && hh < HH && ww >= 0 && ww < WW)
                            hp = cen[i][j] - v3a[i][j] * (r3h[i] * r3w[j]);
                        hpv[j] = hp;
                    }
                    __half2* trow = reinterpret_cast<__half2*>(&tmp[(pr * 4 + i) * 68 + pc * 4]);
                    trow[0] = __floats2half2_rn(hpv[0], hpv[1]);
                    trow[1] = __floats2half2_rn(hpv[2], hpv[3]);
                }
            }
        }
        __syncthreads();

        // ---------------- 3x3 depthwise conv over tmp (fp16 -> f32) ----------------
        const float* __restrict__ wp = ((g == 1) ? w_mf : w_hf) + ci * 9;
        float wk[9];
        #pragma unroll
        for (int t = 0; t < 9; ++t) wk[t] = wp[t];
        #pragma unroll
        for (int i = 0; i < 4; ++i)
            #pragma unroll
            for (int j = 0; j < 4; ++j) acc[i][j] = 0.f;

        #pragma unroll
        for (int rr = 0; rr < 6; ++rr) {
            // tmp row coord = qr-1+rr -> idx qr+rr; cols coord qc-1.. -> idx qc..qc+5
            const __half2* hrow = reinterpret_cast<const __half2*>(&tmp[(qr + rr) * 68 + qc]);
            const float2 va = __half22float2(hrow[0]);
            const float2 vb = __half22float2(hrow[1]);
            const float2 vc = __half22float2(hrow[2]);
            float v[6];
            v[0] = va.x; v[1] = va.y; v[2] = vb.x; v[3] = vb.y; v[4] = vc.x; v[5] = vc.y;
            #pragma unroll
            for (int i = 0; i < 4; ++i) {
                const int ki = rr - i;
                if (ki >= 0 && ki < 3) {
                    #pragma unroll
                    for (int j = 0; j < 4; ++j)
                        acc[i][j] += v[j + 0] * wk[ki * 3 + 0]
                                   + v[j + 1] * wk[ki * 3 + 1]
                                   + v[j + 2] * wk[ki * 3 + 2];
                }
            }
        }
    }

    // ---------------- BN + SiLU + store (channel-shuffled) ----------------
    const float bninv  = gamma[c_out] * rsqrtf(var[c_out] + 1e-5f);
    const float bnbias = beta[c_out] - mean[c_out] * bninv;
    float* __restrict__ op = out + (((size_t)b * CC + c_out) * (size_t)HH + (th + qr)) * (size_t)WW + (tw + qc);
    #pragma unroll
    for (int i = 0; i < 4; ++i) {
        float4 o;
        o.x = silu_of(acc[i][0] * bninv + bnbias);
        o.y = silu_of(acc[i][1] * bninv + bnbias);
        o.z = silu_of(acc[i][2] * bninv + bnbias);
        o.w = silu_of(acc[i][3] * bninv + bnbias);
        *reinterpret_cast<float4*>(op + (size_t)i * WW) = o;
    }
}

extern "C" void kernel_launch(void* const* d_in, const int* in_sizes, int n_in,
                              void* d_out, int out_size, void* d_ws, size_t ws_size,
                              hipStream_t stream) {
    const float* x     = (const float*)d_in[0];
    const float* w_lo  = (const float*)d_in[1];
    const float* w_mf  = (const float*)d_in[2];
    const float* w_hf  = (const float*)d_in[3];
    const float* gam   = (const float*)d_in[4];
    const float* bet   = (const float*)d_in[5];
    const float* mea   = (const float*)d_in[6];
    const float* va    = (const float*)d_in[7];
    float* out = (float*)d_out;

    dim3 grid(16, CC, BB);
    dim3 block(256);
    hipLaunchKernelGGL(trifreq_kernel, grid, block, 0, stream,
                       x, w_lo, w_mf, w_hf, gam, bet, mea, va, out);
}

// Round 6
// 378.684 us; speedup vs baseline: 1.3351x; 1.0574x over previous
//
#include <hip/hip_runtime.h>

#define HH 256
#define WW 256
#define CC 96
#define BB 8

__device__ __forceinline__ float silu_of(float z) {
    return z / (1.0f + __expf(-z));
}

// launch_bounds (256,4): allocator budget 128 VGPR -> no spill. (256,5)
// spilled catastrophically (R2: +580 MB scratch traffic). Keep at 4.
// DO NOT add branchy "interior fast path" reciprocal init: divergent-CF
// merges of the r3h/r7h arrays demote them to scratch (R2/R3/R4).
// Validation gate each round: FETCH ~191 MB, WRITE ~205 MB. Anything above
// is spill traffic.
__global__ __launch_bounds__(256, 4)
void trifreq_kernel(const float* __restrict__ x,
                    const float* __restrict__ w_lo,
                    const float* __restrict__ w_mf,
                    const float* __restrict__ w_hf,
                    const float* __restrict__ gamma,
                    const float* __restrict__ beta,
                    const float* __restrict__ mean,
                    const float* __restrict__ var,
                    float* __restrict__ out)
{
    // xs: input tile, tile-rel coords -4..67 -> row idx = coord+4, col idx =
    // coord+4. Row STRIDE 76 (not 72): 76 = 12 mod 32 banks staggers the
    // 5x5-conv row groups; band-patch stride 5*76 = 380 = 28 mod 32 staggers
    // pr-groups (stride 72 put all pr-groups on bank phase 0 -> the R1
    // conflict source). Words 72..75 of each row + rows 72,73 are
    // uninitialized over-read pads; garbage feeds only write-masked outputs.
    __shared__ __align__(16) float xs[74 * 76];       // 22.50 KB
    // tmp: band values, row idx = coord+1 (coords -1..64, 66 rows exactly =
    // what the 3x3 conv reads), col idx = coord+1, stride 68 (cols 66,67 =
    // write-only ring from pc=16 b128 stores). fp32 (fp16 regressed, R5).
    __shared__ __align__(16) float tmp[66 * 68];      // 17.95 KB (total 40.4 KB -> 4 blocks/CU)

    const int tid = threadIdx.x;
    const int tileIdx = blockIdx.x;          // 0..15
    const int c = blockIdx.y;                // 0..95 (concat order == input channel)
    const int b = blockIdx.z;                // 0..7
    const int th = (tileIdx >> 2) * 64;      // tile origin h
    const int tw = (tileIdx & 3) * 64;       // tile origin w

    const int g = c >> 5;                    // 0=lo,1=mf,2=hf
    const int ci = c & 31;
    const int c_out = ci * 3 + g;            // channel-shuffle output index

    const float* __restrict__ xin = x + (((size_t)b * CC + c) * (size_t)HH) * (size_t)WW;

    // ---------------- stage input tile + halo(4), zero outside image ----------------
    // 72 rows x 18 float4; LDS word = r*76 + 4*c4 (16B aligned).
    for (int idx = tid; idx < 72 * 18; idx += 256) {
        const int r  = idx / 18;
        const int c4 = idx % 18;
        const int gh = th - 4 + r;
        const int gw = tw - 4 + 4 * c4;
        float4 v = make_float4(0.f, 0.f, 0.f, 0.f);
        if (gh >= 0 && gh < HH && gw >= 0 && gw + 3 < WW) {
            v = *reinterpret_cast<const float4*>(xin + (size_t)gh * WW + gw);
        }
        *reinterpret_cast<float4*>(&xs[r * 76 + 4 * c4]) = v;
    }
    __syncthreads();

    const int qr = (tid >> 4) << 2;   // output patch base row (0..60)
    const int qc = (tid & 15) << 2;   // output patch base col (0..60)
    float acc[4][4];

    if (g == 0) {
        // ---------------- low band: direct 5x5 depthwise conv ----------------
        const float* __restrict__ wp = w_lo + ci * 25;
        float wk[25];
        #pragma unroll
        for (int t = 0; t < 25; ++t) wk[t] = wp[t];
        #pragma unroll
        for (int i = 0; i < 4; ++i)
            #pragma unroll
            for (int j = 0; j < 4; ++j) acc[i][j] = 0.f;

        #pragma unroll
        for (int rr = 0; rr < 8; ++rr) {
            const float* row = &xs[(qr + rr + 2) * 76 + qc];
            float v[12];
            *reinterpret_cast<float4*>(&v[0]) = *reinterpret_cast<const float4*>(row);
            *reinterpret_cast<float4*>(&v[4]) = *reinterpret_cast<const float4*>(row + 4);
            *reinterpret_cast<float4*>(&v[8]) = *reinterpret_cast<const float4*>(row + 8);
            #pragma unroll
            for (int i = 0; i < 4; ++i) {
                const int ki = rr - i;
                if (ki >= 0 && ki < 5) {
                    #pragma unroll
                    for (int j = 0; j < 4; ++j)
                        acc[i][j] += v[j + 2] * wk[ki * 5 + 0]
                                   + v[j + 3] * wk[ki * 5 + 1]
                                   + v[j + 4] * wk[ki * 5 + 2]
                                   + v[j + 5] * wk[ki * 5 + 3]
                                   + v[j + 6] * wk[ki * 5 + 4];
                }
            }
        }
    } else {
        // ---------------- band stage: ONE pass, 14x17 = 238 patches of 5x4 ----------------
        // (R1 did 289 patches in 2 passes: pass 2 had 33/256 threads active ->
        //  band critical path was 2x patch-time for 1.13x work.)
        if (tid < 238) {
            const int pr = tid / 17;          // 0..13
            const int pc = tid % 17;          // 0..16
            const int br = pr * 5 - 1;        // band row coord of i=0
            const int bc = pc * 4 - 1;        // band col coord of j=0

            if (g == 1) {
                // ---- mid band: bandpass = avg3 - avg7 ----
                float v7a[5][4] = {};
                float v3a[5][4] = {};
                #pragma unroll
                for (int rr = 0; rr < 11; ++rr) {
                    // row coord = br-3+rr -> xs row idx 5*pr+rr; clamp to 73
                    // (pr=13 reads rows 74,75 -> feed only write-masked outputs)
                    const int xr = min(5 * pr + rr, 73);
                    const float* row = &xs[xr * 76 + pc * 4];
                    float v[12];
                    *reinterpret_cast<float4*>(&v[0]) = *reinterpret_cast<const float4*>(row);
                    *reinterpret_cast<float4*>(&v[4]) = *reinterpret_cast<const float4*>(row + 4);
                    *reinterpret_cast<float4*>(&v[8]) = *reinterpret_cast<const float4*>(row + 8);
                    float h7[4], h3[4];
                    float s = v[0] + v[1] + v[2] + v[3] + v[4] + v[5] + v[6];
                    h7[0] = s;
                    h7[1] = h7[0] + v[7] - v[0];
                    h7[2] = h7[1] + v[8] - v[1];
                    h7[3] = h7[2] + v[9] - v[2];
                    #pragma unroll
                    for (int j = 0; j < 4; ++j) h3[j] = v[j + 2] + v[j + 3] + v[j + 4];
                    #pragma unroll
                    for (int k = 0; k < 5; ++k) {
                        if (rr >= k && rr <= k + 6) {         // pool7 rows: rr = k..k+6
                            #pragma unroll
                            for (int j = 0; j < 4; ++j) v7a[k][j] += h7[j];
                        }
                        if (rr >= k + 2 && rr <= k + 4) {     // pool3 rows: rr = k+2..k+4
                            #pragma unroll
                            for (int j = 0; j < 4; ++j) v3a[k][j] += h3[j];
                        }
                    }
                }
                // count_include_pad=False reciprocals (unconditional — see note)
                float r3h[5], r7h[5], r3w[4], r7w[4];
                #pragma unroll
                for (int i = 0; i < 5; ++i) {
                    const int hh = th + br + i;
                    const int a3 = min(hh + 1, HH - 1) - max(hh - 1, 0) + 1;
                    const int a7 = min(hh + 3, HH - 1) - max(hh - 3, 0) + 1;
                    r3h[i] = 1.0f / (float)a3;
                    r7h[i] = 1.0f / (float)a7;
                }
                #pragma unroll
                for (int j = 0; j < 4; ++j) {
                    const int ww = tw + bc + j;
                    const int a3 = min(ww + 1, WW - 1) - max(ww - 1, 0) + 1;
                    const int a7 = min(ww + 3, WW - 1) - max(ww - 3, 0) + 1;
                    r3w[j] = 1.0f / (float)a3;
                    r7w[j] = 1.0f / (float)a7;
                }
                #pragma unroll
                for (int i = 0; i < 5; ++i) {
                    const int orow = pr * 5 + i;      // tmp row idx = coord+1
                    if (orow < 66) {
                        const int hh = th + br + i;
                        float bpv[4];
                        #pragma unroll
                        for (int j = 0; j < 4; ++j) {
                            const int ww = tw + bc + j;
                            float bp = 0.f;
                            if (hh >= 0 && hh < HH && ww >= 0 && ww < WW)
                                bp = v3a[i][j] * (r3h[i] * r3w[j]) - v7a[i][j] * (r7h[i] * r7w[j]);
                            bpv[j] = bp;
                        }
                        *reinterpret_cast<float4*>(&tmp[orow * 68 + pc * 4]) =
                            make_float4(bpv[0], bpv[1], bpv[2], bpv[3]);
                    }
                }
            } else {
                // ---- high band: highpass = x - avg3 ----
                float v3a[5][4] = {};
                float cen[5][4];
                #pragma unroll
                for (int rr = 0; rr < 7; ++rr) {
                    // row coord = br-1+rr -> xs row idx 5*pr+2+rr (max 73, in range)
                    const float* row = &xs[(5 * pr + 2 + rr) * 76 + pc * 4];
                    float v[8];
                    *reinterpret_cast<float4*>(&v[0]) = *reinterpret_cast<const float4*>(row);
                    *reinterpret_cast<float4*>(&v[4]) = *reinterpret_cast<const float4*>(row + 4);
                    float h3[4];
                    #pragma unroll
                    for (int j = 0; j < 4; ++j) h3[j] = v[j + 2] + v[j + 3] + v[j + 4];
                    if (rr >= 1 && rr <= 5) {
                        #pragma unroll
                        for (int j = 0; j < 4; ++j) cen[rr - 1][j] = v[j + 3];
                    }
                    #pragma unroll
                    for (int k = 0; k < 5; ++k) {
                        if (rr >= k && rr <= k + 2) {
                            #pragma unroll
                            for (int j = 0; j < 4; ++j) v3a[k][j] += h3[j];
                        }
                    }
                }
                float r3h[5], r3w[4];
                #pragma unroll
                for (int i = 0; i < 5; ++i) {
                    const int hh = th + br + i;
                    const int a3 = min(hh + 1, HH - 1) - max(hh - 1, 0) + 1;
                    r3h[i] = 1.0f / (float)a3;
                }
                #pragma unroll
                for (int j = 0; j < 4; ++j) {
                    const int ww = tw + bc + j;
                    const int a3 = min(ww + 1, WW - 1) - max(ww - 1, 0) + 1;
                    r3w[j] = 1.0f / (float)a3;
                }
                #pragma unroll
                for (int i = 0; i < 5; ++i) {
                    const int orow = pr * 5 + i;
                    if (orow < 66) {
                        const int hh = th + br + i;
                        float hpv[4];
                        #pragma unroll
                        for (int j = 0; j < 4; ++j) {
                            const int ww = tw + bc + j;
                            float hp = 0.f;
                            if (hh >= 0 && hh < HH && ww >= 0 && ww < WW)
                                hp = cen[i][j] - v3a[i][j] * (r3h[i] * r3w[j]);
                            hpv[j] = hp;
                        }
                        *reinterpret_cast<float4*>(&tmp[orow * 68 + pc * 4]) =
                            make_float4(hpv[0], hpv[1], hpv[2], hpv[3]);
                    }
                }
            }
        }
        __syncthreads();

        // ---------------- 3x3 depthwise conv over tmp ----------------
        const float* __restrict__ wp = ((g == 1) ? w_mf : w_hf) + ci * 9;
        float wk[9];
        #pragma unroll
        for (int t = 0; t < 9; ++t) wk[t] = wp[t];
        #pragma unroll
        for (int i = 0; i < 4; ++i)
            #pragma unroll
            for (int j = 0; j < 4; ++j) acc[i][j] = 0.f;

        #pragma unroll
        for (int rr = 0; rr < 6; ++rr) {
            // band row coord = qr-1+rr -> tmp row idx qr+rr (max 65 ✓);
            // cols coord qc-1.. -> idx qc..qc+5, two b128 (lanes 6,7 padding)
            const float* row = &tmp[(qr + rr) * 68 + qc];
            float v[8];
            *reinterpret_cast<float4*>(&v[0]) = *reinterpret_cast<const float4*>(row);
            *reinterpret_cast<float4*>(&v[4]) = *reinterpret_cast<const float4*>(row + 4);
            #pragma unroll
            for (int i = 0; i < 4; ++i) {
                const int ki = rr - i;
                if (ki >= 0 && ki < 3) {
                    #pragma unroll
                    for (int j = 0; j < 4; ++j)
                        acc[i][j] += v[j + 0] * wk[ki * 3 + 0]
                                   + v[j + 1] * wk[ki * 3 + 1]
                                   + v[j + 2] * wk[ki * 3 + 2];
                }
            }
        }
    }

    // ---------------- BN + SiLU + store (channel-shuffled) ----------------
    const float bninv  = gamma[c_out] * rsqrtf(var[c_out] + 1e-5f);
    const float bnbias = beta[c_out] - mean[c_out] * bninv;
    float* __restrict__ op = out + (((size_t)b * CC + c_out) * (size_t)HH + (th + qr)) * (size_t)WW + (tw + qc);
    #pragma unroll
    for (int i = 0; i < 4; ++i) {
        float4 o;
        o.x = silu_of(acc[i][0] * bninv + bnbias);
        o.y = silu_of(acc[i][1] * bninv + bnbias);
        o.z = silu_of(acc[i][2] * bninv + bnbias);
        o.w = silu_of(acc[i][3] * bninv + bnbias);
        *reinterpret_cast<float4*>(op + (size_t)i * WW) = o;
    }
}

extern "C" void kernel_launch(void* const* d_in, const int* in_sizes, int n_in,
                              void* d_out, int out_size, void* d_ws, size_t ws_size,
                              hipStream_t stream) {
    const float* x     = (const float*)d_in[0];
    const float* w_lo  = (const float*)d_in[1];
    const float* w_mf  = (const float*)d_in[2];
    const float* w_hf  = (const float*)d_in[3];
    const float* gam   = (const float*)d_in[4];
    const float* bet   = (const float*)d_in[5];
    const float* mea   = (const float*)d_in[6];
    const float* va    = (const float*)d_in[7];
    float* out = (float*)d_out;

    dim3 grid(16, CC, BB);
    dim3 block(256);
    hipLaunchKernelGGL(trifreq_kernel, grid, block, 0, stream,
                       x, w_lo, w_mf, w_hf, gam, bet, mea, va, out);
}